// Round 9
// baseline (159.174 us; speedup 1.0000x reference)
//
#include <hip/hip_runtime.h>

// StochaPolicy: out[b,0:32] = phi_m @ w_m.T + b_m ; out[b,32:64] = exp(clip(phi_s @ w_s.T + b_s))
// phi_h[b,k] = exp(-(|x|^2 - 2 x.C_h[k] + |C_h[k]|^2) / (2|sigma_h[k]|))
// B=32768 D=256 K=1024 A=32.
//
// R9: R8's barrier-free pipelined i8/fp8 K-loop, with the per-wave tile halved
// (wave = kc-16 x b-32; block = 256 thr over 32 obs rows; grid 1024) so regs
// drop ~190->~150 and __launch_bounds__(256,3) yields 3 waves/SIMD instead of
// 2. Total work per SIMD unchanged (split by b, nothing duplicated except
// L2-hot cf/w/scalar loads); +50% independent streams to fill the ~55% idle
// that in-wave pipelining (R8) could not. R5's occupancy test was confounded
// by per-pair lockstep barriers; this one is barrier-free.

typedef float floatx4 __attribute__((ext_vector_type(4)));
typedef int   intx4  __attribute__((ext_vector_type(4)));
typedef unsigned int u32;
typedef unsigned char u8;

constexpr float LOG2E = 1.4426950408889634f;
constexpr float QS    = 25.4f;                 // 127/5 quant multiplier
constexpr float SINV2 = (5.0f / 127.0f) * (5.0f / 127.0f);

__device__ __forceinline__ u32 pk_fp8(float a, float b, float c, float d) {
  u32 v = __builtin_amdgcn_cvt_pk_fp8_f32(a, b, 0u, 0);   // bytes 0,1
  v = __builtin_amdgcn_cvt_pk_fp8_f32(c, d, v, 1);        // bytes 2,3
  return v;
}
__device__ __forceinline__ long mk64(u32 lo, u32 hi) {
  return (long)lo | ((long)hi << 32);
}
__device__ __forceinline__ int q8(float x) {
  return (int)rintf(fminf(fmaxf(x * QS, -127.f), 127.f));
}
__device__ __forceinline__ u32 pk_i8(int a, int b, int c, int d) {
  return (u32)(a & 255) | ((u32)(b & 255) << 8) | ((u32)(c & 255) << 16) | ((u32)(d & 255) << 24);
}

// ---------- merged prologue (identical to R7/R8) ----------
__global__ void prep(const float* __restrict__ mC, const float* __restrict__ mS,
                     const float* __restrict__ sC, const float* __restrict__ sS,
                     const float* __restrict__ mw, const float* __restrict__ sw,
                     u8* __restrict__ Cb2, float* __restrict__ a2g,
                     float* __restrict__ g2n, u8* __restrict__ wb)
{
  const int blk = blockIdx.x;
  if (blk < 512) {
    const int wq = threadIdx.x >> 6;
    const int t  = threadIdx.x & 63;
    const int b  = blk * 4 + wq;            // 0..2047 combined center index
    const int half = b >> 10;
    const int k = b & 1023;
    const float* src = (half ? sC : mC) + (size_t)k * 256;
    float4 f = *(const float4*)(src + t * 4);
    int i0 = q8(f.x), i1 = q8(f.y), i2 = q8(f.z), i3 = q8(f.w);
    const int ct = b >> 6, row = b & 63;
    const int wvv = row >> 4, cc = row & 15;
    const int ks = t >> 4, qq = (t >> 2) & 3, j0 = (t & 3) * 4;
    *(u32*)(Cb2 + (size_t)ct * 16384 + wvv * 4096 + (16 * qq + cc) * 64 + 16 * ks + j0) =
        pk_i8(i0, i1, i2, i3);
    int is = i0 * i0 + i1 * i1 + i2 * i2 + i3 * i3;
    for (int off = 32; off > 0; off >>= 1) is += __shfl_down(is, off, 64);
    if (t == 0) {
      float sig = fabsf((half ? sS : mS)[k]);
      float t2 = SINV2 * LOG2E * 0.5f / sig;
      a2g[b] = 2.f * t2;
      g2n[b] = -t2 * (float)is;
    }
  } else {
    int i0 = (blk - 512) * 1024 + threadIdx.x * 4;   // 0..65532
    int half = i0 >> 15;
    int rem  = i0 & 32767;
    const float* src = half ? sw : mw;
    float4 f = *(const float4*)(src + rem);
    ((u32*)wb)[i0 >> 2] = pk_fp8(f.x, f.y, f.z, f.w);
  }
}

// ---------- main fused kernel ----------
__global__ __launch_bounds__(256, 3)
void policy_main(const float* __restrict__ obs,
                 const u8* __restrict__ Cb2,
                 const float* __restrict__ a2g,
                 const float* __restrict__ g2n,
                 const u8* __restrict__ wb,
                 const float* __restrict__ mbias,
                 const float* __restrict__ sbias,
                 float* __restrict__ out)
{
  // LDS: prologue obs i8 tile [0,8192) + x2p [8192, 8192+2176).
  // Epilogue red[4][32][68] f32 (34816 B) aliases from 0.
  __shared__ __align__(16) char smem[34816];
  float* x2p = (float*)(smem + 8192);
  float* red = (float*)smem;

  const int tid  = threadIdx.x;
  const int lane = tid & 63;
  const int wv   = tid >> 6;        // wave 0..3 : kc slice [16wv,16wv+16)
  const int c    = lane & 15;
  const int q    = lane >> 4;       // quad 0..3
  const int row0 = blockIdx.x * 32; // 32 obs rows per block
  const int kslc = 16 * wv + 4 * q; // lane's kc sub-slice base within tile
  const int cfo  = tid * 64;        // = wv*4096 + lane*64 : lane's fragment bytes

#define LOADCF(CF, t)                                                     \
  { const u8* g0_ = Cb2 + (size_t)(t) * 16384 + cfo;                      \
    CF[0] = *(const intx4*)(g0_);                                         \
    CF[1] = *(const intx4*)(g0_ + 16);                                    \
    CF[2] = *(const intx4*)(g0_ + 32);                                    \
    CF[3] = *(const intx4*)(g0_ + 48); }

  intx4 cfU[4], cfV[4];
  LOADCF(cfU, 0)
  LOADCF(cfV, 1)

  // ---- convert obs tile (32 rows) fp32 -> i8 into LDS (XOR-swizzled) + x2 ----
  #pragma unroll
  for (int i = 0; i < 2; ++i) {
    int s = i * 256 + tid;          // 16B slot 0..511
    int row = s >> 4;               // 0..31
    int s16 = s & 15;
    int l16 = s16 ^ (row & 15);
    const float* src = obs + (size_t)(row0 + row) * 256 + l16 * 16;
    float4 f0 = ((const float4*)src)[0];
    float4 f1 = ((const float4*)src)[1];
    float4 f2 = ((const float4*)src)[2];
    float4 f3 = ((const float4*)src)[3];
    int a0 = q8(f0.x), a1v = q8(f0.y), a2v = q8(f0.z), a3 = q8(f0.w);
    int b0 = q8(f1.x), b1 = q8(f1.y), b2 = q8(f1.z), b3 = q8(f1.w);
    int c0 = q8(f2.x), c1 = q8(f2.y), c2 = q8(f2.z), c3 = q8(f2.w);
    int d0 = q8(f3.x), d1 = q8(f3.y), d2 = q8(f3.z), d3 = q8(f3.w);
    uint4 pk;
    pk.x = pk_i8(a0, a1v, a2v, a3);
    pk.y = pk_i8(b0, b1, b2, b3);
    pk.z = pk_i8(c0, c1, c2, c3);
    pk.w = pk_i8(d0, d1, d2, d3);
    *(uint4*)(smem + s * 16) = pk;
    int is = a0*a0 + a1v*a1v + a2v*a2v + a3*a3
           + b0*b0 + b1*b1 + b2*b2 + b3*b3
           + c0*c0 + c1*c1 + c2*c2 + c3*c3
           + d0*d0 + d1*d1 + d2*d2 + d3*d3;
    x2p[row * 16 + s16] = (float)is;
  }
  __syncthreads();   // obs tile + partials visible

  // ---- preload obs B-fragments: ob[nt][ks] = obs[b=nt*16+c][d=64ks+16q..+16] ----
  intx4 ob[2][4];                   // 32 regs (MFMA operands)
  #pragma unroll
  for (int nt = 0; nt < 2; ++nt) {
    const int row = nt * 16 + c;
    #pragma unroll
    for (int ks = 0; ks < 4; ++ks) {
      int slot = (4 * ks + q) ^ (row & 15);
      ob[nt][ks] = *(const intx4*)(smem + row * 256 + slot * 16);
    }
  }
  if (tid < 32) {
    float s = 0.f;
    #pragma unroll
    for (int j = 0; j < 16; j += 4) {
      float4 a = *(const float4*)(x2p + tid * 16 + j);
      s += a.x + a.y + a.z + a.w;
    }
    x2p[512 + tid] = s;
  }
  __syncthreads();   // x2 sums visible (last barrier before epilogue)

  float hx2[2];
  #pragma unroll
  for (int nt = 0; nt < 2; ++nt) hx2[nt] = 0.5f * x2p[512 + nt * 16 + c];

  const intx4 Z4i = {0, 0, 0, 0};
  const floatx4 Z4 = {0.f, 0.f, 0.f, 0.f};
  floatx4 acc2m[2][2], acc2s[2][2];   // 32 regs (AGPR), static indexing only
  #pragma unroll
  for (int a2i = 0; a2i < 2; ++a2i)
    #pragma unroll
    for (int nt = 0; nt < 2; ++nt) {
      acc2m[a2i][nt] = Z4;
      acc2s[a2i][nt] = Z4;
    }

  intx4 a1A[2], a1B[2];
  float4 acA, gcA, acB, gcB;
  u32 pE[2], pc[2];

#define GEMM1T(CF, A1)                                                          \
  { A1[0] = __builtin_amdgcn_mfma_i32_16x16x64_i8(CF[0], ob[0][0], Z4i, 0, 0, 0); \
    A1[1] = __builtin_amdgcn_mfma_i32_16x16x64_i8(CF[0], ob[1][0], Z4i, 0, 0, 0); \
    _Pragma("unroll")                                                           \
    for (int ks = 1; ks < 4; ++ks) {                                            \
      A1[0] = __builtin_amdgcn_mfma_i32_16x16x64_i8(CF[ks], ob[0][ks], A1[0], 0, 0, 0); \
      A1[1] = __builtin_amdgcn_mfma_i32_16x16x64_i8(CF[ks], ob[1][ks], A1[1], 0, 0, 0); \
    } }

#define EXPP(A1, AC, GC, DST)                                                   \
  { _Pragma("unroll")                                                           \
    for (int nt = 0; nt < 2; ++nt) {                                            \
      float t0 = (float)A1[nt][0] - hx2[nt], t1 = (float)A1[nt][1] - hx2[nt];   \
      float t2 = (float)A1[nt][2] - hx2[nt], t3 = (float)A1[nt][3] - hx2[nt];   \
      DST[nt] = pk_fp8(__builtin_amdgcn_exp2f(fmaf(AC.x, t0, GC.x)),            \
                       __builtin_amdgcn_exp2f(fmaf(AC.y, t1, GC.y)),            \
                       __builtin_amdgcn_exp2f(fmaf(AC.z, t2, GC.z)),            \
                       __builtin_amdgcn_exp2f(fmaf(AC.w, t3, GC.w))); } }

#define GEMM2P(ACC, W0L, W0H, W1L, W1H)                                         \
  { long wA0 = mk64(W0L, W0H), wA1 = mk64(W1L, W1H);                            \
    _Pragma("unroll")                                                           \
    for (int nt = 0; nt < 2; ++nt) {                                            \
      long pb = mk64(pE[nt], pc[nt]);                                           \
      ACC[0][nt] = __builtin_amdgcn_mfma_f32_16x16x32_fp8_fp8(wA0, pb, ACC[0][nt], 0, 0, 0); \
      ACC[1][nt] = __builtin_amdgcn_mfma_f32_16x16x32_fp8_fp8(wA1, pb, ACC[1][nt], 0, 0, 0); \
    } }

  // pipeline prologue: tile0 GEMM1 issued, cfU refilled with tile2
  acA = *(const float4*)(a2g + kslc);
  gcA = *(const float4*)(g2n + kslc);
  GEMM1T(cfU, a1A)
  LOADCF(cfU, 2)

  // STEP(m): GEMM1(2m+1) ; exp(2m) ; GEMM1(2m+2) ; exp(2m+1) ; GEMM2(pair m)
#define STEP(m, ACC, HB, DO_U)                                                  \
  {                                                                             \
    const int e = 2 * (m);                                                      \
    const int kbE = (e & 15) * 64 + kslc;                                       \
    const u8* wr0 = wb + (size_t)((HB) + c) * 1024 + kbE;                       \
    const u8* wr1 = wb + (size_t)((HB) + 16 + c) * 1024 + kbE;                  \
    u32 w0lo = *(const u32*)wr0, w0hi = *(const u32*)(wr0 + 64);                \
    u32 w1lo = *(const u32*)wr1, w1hi = *(const u32*)(wr1 + 64);                \
    acB = *(const float4*)(a2g + (e + 1) * 64 + kslc);                          \
    gcB = *(const float4*)(g2n + (e + 1) * 64 + kslc);                          \
    GEMM1T(cfV, a1B)                                                            \
    LOADCF(cfV, e + 3)                                                          \
    EXPP(a1A, acA, gcA, pE)                                                     \
    acA = *(const float4*)(a2g + (e + 2) * 64 + kslc);                          \
    gcA = *(const float4*)(g2n + (e + 2) * 64 + kslc);                          \
    GEMM1T(cfU, a1A)                                                            \
    if (DO_U) LOADCF(cfU, e + 4)                                                \
    EXPP(a1B, acB, gcB, pc)                                                     \
    GEMM2P(ACC, w0lo, w0hi, w1lo, w1hi)                                         \
  }

  #pragma unroll
  for (int m = 0; m < 8; ++m) STEP(m, acc2m, 0, 1)
  #pragma unroll
  for (int m = 8; m < 14; ++m) STEP(m, acc2s, 32, 1)
  STEP(14, acc2s, 32, 0)
  // last pair: tiles 30 (in a1A) and 31 (via cfV)
  {
    const int kbE = (30 & 15) * 64 + kslc;
    const u8* wr0 = wb + (size_t)(32 + c) * 1024 + kbE;
    const u8* wr1 = wb + (size_t)(48 + c) * 1024 + kbE;
    u32 w0lo = *(const u32*)wr0, w0hi = *(const u32*)(wr0 + 64);
    u32 w1lo = *(const u32*)wr1, w1hi = *(const u32*)(wr1 + 64);
    acB = *(const float4*)(a2g + 31 * 64 + kslc);
    gcB = *(const float4*)(g2n + 31 * 64 + kslc);
    GEMM1T(cfV, a1B)
    EXPP(a1A, acA, gcA, pE)
    EXPP(a1B, acB, gcB, pc)
    GEMM2P(acc2s, w0lo, w0hi, w1lo, w1hi)
  }
#undef STEP
#undef GEMM1T
#undef EXPP
#undef GEMM2P
#undef LOADCF

  // ---- epilogue: cross-wave reduction (red aliases obs LDS) ----
  // red[wv][bl=32][a=68pad]; lane(c,q) reg r holds a = h*32+a2i*16+4q+r, bl = nt*16+c
  {
    float* myr = red + wv * 2176;
    #pragma unroll
    for (int a2i = 0; a2i < 2; ++a2i)
      #pragma unroll
      for (int nt = 0; nt < 2; ++nt) {
        *(floatx4*)(myr + (nt * 16 + c) * 68 + a2i * 16 + 4 * q)      = acc2m[a2i][nt];
        *(floatx4*)(myr + (nt * 16 + c) * 68 + 32 + a2i * 16 + 4 * q) = acc2s[a2i][nt];
      }
  }
  __syncthreads();

  #pragma unroll
  for (int i = 0; i < 8; ++i) {
    int idx = tid + 256 * i;        // 0..2047
    int a = idx & 63;
    int b = idx >> 6;               // 0..31
    float v = red[b * 68 + a] + red[2176 + b * 68 + a] +
              red[4352 + b * 68 + a] + red[6528 + b * 68 + a];
    if (a < 32) {
      v += mbias[a];
    } else {
      v += sbias[a - 32];
      v = fminf(fmaxf(v, -20.f), 2.f);
      v = __builtin_amdgcn_exp2f(v * LOG2E);
    }
    out[(size_t)(row0 + b) * 64 + a] = v;
  }
}

extern "C" void kernel_launch(void* const* d_in, const int* in_sizes, int n_in,
                              void* d_out, int out_size, void* d_ws, size_t ws_size,
                              hipStream_t stream) {
  const float* obs = (const float*)d_in[0];
  const float* mC  = (const float*)d_in[1];
  const float* mS  = (const float*)d_in[2];
  const float* mW  = (const float*)d_in[3];
  const float* mB  = (const float*)d_in[4];
  const float* sC  = (const float*)d_in[5];
  const float* sS  = (const float*)d_in[6];
  const float* sW  = (const float*)d_in[7];
  const float* sB  = (const float*)d_in[8];
  float* out = (float*)d_out;

  // workspace: Cb2[2048*256] i8 (512KB) | a2g[2048] f32 | g2n[2048] f32 | wb[65536] fp8
  u8*    Cb2 = (u8*)d_ws;
  float* a2g = (float*)((char*)d_ws + 2048 * 256);
  float* g2n = a2g + 2048;
  u8*    wb  = (u8*)(g2n + 2048);

  prep<<<576, 256, 0, stream>>>(mC, mS, sC, sS, mW, sW, Cb2, a2g, g2n, wb);
  policy_main<<<1024, 256, 0, stream>>>(obs, Cb2, a2g, g2n, wb, mB, sB, out);
}

// Round 10
// 117.110 us; speedup vs baseline: 1.3592x; 1.3592x over previous
//
#include <hip/hip_runtime.h>

// StochaPolicy: out[b,0:32] = phi_m @ w_m.T + b_m ; out[b,32:64] = exp(clip(phi_s @ w_s.T + b_s))
// phi_h[b,k] = exp(-(|x|^2 - 2 x.C_h[k] + |C_h[k]|^2) / (2|sigma_h[k]|))
// B=32768 D=256 K=1024 A=32.
//
// R10: R8's barrier-free pipelined i8/fp8 K-loop with ALL K-loop loads
// coalesced. R9's regression (2x waves -> 2x slower with MfmaUtil down)
// exposed the real bottleneck: TA/L1 line throughput. R6-R8 loads were all
// 64-line gathers (cf: lane-stride 64B; w: lane-stride 1024B). Now:
//  - cf: prep interleaves fragments so chunk j of lane l is at (j*64+l)*16
//    -> each dwordx4 is 64 lanes x 16B contiguous (16 lines, was 64).
//  - w: prep builds wt[pair][tid] = the lane's exact 16B GEMM2 A-operand
//    -> ONE coalesced dwordx4 per pair (was 4 x 64-line gathers).
// ~4x fewer line-touches per pair; math bit-identical to R8.

typedef float floatx4 __attribute__((ext_vector_type(4)));
typedef int   intx4  __attribute__((ext_vector_type(4)));
typedef unsigned int u32;
typedef unsigned char u8;

constexpr float LOG2E = 1.4426950408889634f;
constexpr float QS    = 25.4f;                 // 127/5 quant multiplier
constexpr float SINV2 = (5.0f / 127.0f) * (5.0f / 127.0f);

__device__ __forceinline__ u32 pk_fp8(float a, float b, float c, float d) {
  u32 v = __builtin_amdgcn_cvt_pk_fp8_f32(a, b, 0u, 0);   // bytes 0,1
  v = __builtin_amdgcn_cvt_pk_fp8_f32(c, d, v, 1);        // bytes 2,3
  return v;
}
__device__ __forceinline__ long mk64(u32 lo, u32 hi) {
  return (long)lo | ((long)hi << 32);
}
__device__ __forceinline__ int q8(float x) {
  return (int)rintf(fminf(fmaxf(x * QS, -127.f), 127.f));
}
__device__ __forceinline__ u32 pk_i8(int a, int b, int c, int d) {
  return (u32)(a & 255) | ((u32)(b & 255) << 8) | ((u32)(c & 255) << 16) | ((u32)(d & 255) << 24);
}

// ---------- merged prologue ----------
// blocks 0..511 (4 centers each): centers -> i8, COALESCED fragment order:
//   value C[16wvv+cc][64ks+16qq+off] at ct*16384 + wvv*4096 + (ks*64+qq*16+cc)*16 + off
//   so kernel lane l reads chunk j at (j*64+l)*16 (64x16B contiguous per instr).
//   Also a2g[k]=2*t2, g2n[k]=-t2*c2i (t2 = s^2*log2e/(2|sigma|), c2i int |c|^2).
// blocks 512..527: wt table: wt[(m*256+tid)*16] = {w0lo,w0hi,w1lo,w1hi} fp8,
//   the exact GEMM2 A-operand for pair m, thread tid.
__global__ void prep(const float* __restrict__ mC, const float* __restrict__ mS,
                     const float* __restrict__ sC, const float* __restrict__ sS,
                     const float* __restrict__ mw, const float* __restrict__ sw,
                     u8* __restrict__ Cb2, float* __restrict__ a2g,
                     float* __restrict__ g2n, u8* __restrict__ wt)
{
  const int blk = blockIdx.x;
  if (blk < 512) {
    const int wq = threadIdx.x >> 6;
    const int t  = threadIdx.x & 63;
    const int b  = blk * 4 + wq;            // 0..2047 combined center index
    const int half = b >> 10;
    const int k = b & 1023;
    const float* src = (half ? sC : mC) + (size_t)k * 256;
    float4 f = *(const float4*)(src + t * 4);
    int i0 = q8(f.x), i1 = q8(f.y), i2 = q8(f.z), i3 = q8(f.w);
    const int ct = b >> 6, row = b & 63;
    const int wvv = row >> 4, cc = row & 15;
    const int ks = t >> 4, qq = (t >> 2) & 3, j0 = (t & 3) * 4;
    *(u32*)(Cb2 + (size_t)ct * 16384 + wvv * 4096 + (ks * 64 + qq * 16 + cc) * 16 + j0) =
        pk_i8(i0, i1, i2, i3);
    int is = i0 * i0 + i1 * i1 + i2 * i2 + i3 * i3;
    for (int off = 32; off > 0; off >>= 1) is += __shfl_down(is, off, 64);
    if (t == 0) {
      float sig = fabsf((half ? sS : mS)[k]);
      float t2 = SINV2 * LOG2E * 0.5f / sig;
      a2g[b] = 2.f * t2;
      g2n[b] = -t2 * (float)is;
    }
  } else {
    // wt builder: block = pair m, thread = tid of the main kernel
    const int m   = blk - 512;              // 0..15
    const int tid = threadIdx.x;
    const int wv  = tid >> 6;
    const int lane = tid & 63;
    const int c   = lane & 15;
    const int q   = lane >> 4;
    const int kbE = ((2 * m) & 15) * 64 + 16 * wv + 4 * q;
    const float* src = (m < 8) ? mw : sw;   // w_h[a][k], A=32 x K=1024
    float4 f00 = *(const float4*)(src + (size_t)c * 1024 + kbE);
    float4 f01 = *(const float4*)(src + (size_t)c * 1024 + kbE + 64);
    float4 f10 = *(const float4*)(src + (size_t)(16 + c) * 1024 + kbE);
    float4 f11 = *(const float4*)(src + (size_t)(16 + c) * 1024 + kbE + 64);
    uint4 o;
    o.x = pk_fp8(f00.x, f00.y, f00.z, f00.w);   // w0lo: even-tile K bytes
    o.y = pk_fp8(f01.x, f01.y, f01.z, f01.w);   // w0hi: odd-tile K bytes
    o.z = pk_fp8(f10.x, f10.y, f10.z, f10.w);   // w1lo
    o.w = pk_fp8(f11.x, f11.y, f11.z, f11.w);   // w1hi
    *(uint4*)(wt + ((size_t)m * 256 + tid) * 16) = o;
  }
}

// ---------- main fused kernel ----------
__global__ __launch_bounds__(256, 2)
void policy_main(const float* __restrict__ obs,
                 const u8* __restrict__ Cb2,
                 const float* __restrict__ a2g,
                 const float* __restrict__ g2n,
                 const u8* __restrict__ wt,
                 const float* __restrict__ mbias,
                 const float* __restrict__ sbias,
                 float* __restrict__ out)
{
  // LDS: prologue obs i8 tile [0,16384) + x2p [16384,20736).
  // Epilogue red[4][64][68] f32 (69632 B) aliases from 0.
  __shared__ __align__(16) char smem[69888];
  float* x2p = (float*)(smem + 16384);
  float* red = (float*)smem;

  const int tid  = threadIdx.x;
  const int lane = tid & 63;
  const int wv   = tid >> 6;        // wave 0..3 : kc slice [16wv,16wv+16)
  const int c    = lane & 15;
  const int q    = lane >> 4;       // quad 0..3
  const int row0 = blockIdx.x * 64;
  const int kslc = 16 * wv + 4 * q; // lane's kc sub-slice base within tile
  const int cfo  = wv * 4096 + lane * 16;  // coalesced fragment base
  const u8* wtl  = wt + (size_t)tid * 16;  // lane's wt column

  // chunk j of this lane's tile-fragment lives at cfo + j*1024 (coalesced)
#define LOADCF(CF, t)                                                     \
  { const u8* g0_ = Cb2 + (size_t)(t) * 16384 + cfo;                      \
    CF[0] = *(const intx4*)(g0_);                                         \
    CF[1] = *(const intx4*)(g0_ + 1024);                                  \
    CF[2] = *(const intx4*)(g0_ + 2048);                                  \
    CF[3] = *(const intx4*)(g0_ + 3072); }

  intx4 cfU[4], cfV[4];
  LOADCF(cfU, 0)
  LOADCF(cfV, 1)

  // ---- convert obs tile fp32 -> i8 into LDS (XOR-swizzled 16B slots) + x2 ----
  #pragma unroll
  for (int i = 0; i < 4; ++i) {
    int s = i * 256 + tid;          // 16B slot 0..1023
    int row = s >> 4;
    int s16 = s & 15;
    int l16 = s16 ^ (row & 15);
    const float* src = obs + (size_t)(row0 + row) * 256 + l16 * 16;
    float4 f0 = ((const float4*)src)[0];
    float4 f1 = ((const float4*)src)[1];
    float4 f2 = ((const float4*)src)[2];
    float4 f3 = ((const float4*)src)[3];
    int a0 = q8(f0.x), a1v = q8(f0.y), a2v = q8(f0.z), a3 = q8(f0.w);
    int b0 = q8(f1.x), b1 = q8(f1.y), b2 = q8(f1.z), b3 = q8(f1.w);
    int c0 = q8(f2.x), c1 = q8(f2.y), c2 = q8(f2.z), c3 = q8(f2.w);
    int d0 = q8(f3.x), d1 = q8(f3.y), d2 = q8(f3.z), d3 = q8(f3.w);
    uint4 pk;
    pk.x = pk_i8(a0, a1v, a2v, a3);
    pk.y = pk_i8(b0, b1, b2, b3);
    pk.z = pk_i8(c0, c1, c2, c3);
    pk.w = pk_i8(d0, d1, d2, d3);
    *(uint4*)(smem + s * 16) = pk;
    int is = a0*a0 + a1v*a1v + a2v*a2v + a3*a3
           + b0*b0 + b1*b1 + b2*b2 + b3*b3
           + c0*c0 + c1*c1 + c2*c2 + c3*c3
           + d0*d0 + d1*d1 + d2*d2 + d3*d3;
    x2p[row * 16 + s16] = (float)is;
  }
  __syncthreads();   // obs tile + partials visible

  // ---- preload obs B-fragments: ob[nt][ks] = obs[b=nt*16+c][d=64ks+16q..+16] ----
  intx4 ob[4][4];                   // 64 regs (MFMA operands)
  #pragma unroll
  for (int nt = 0; nt < 4; ++nt) {
    const int row = nt * 16 + c;
    #pragma unroll
    for (int ks = 0; ks < 4; ++ks) {
      int slot = (4 * ks + q) ^ (row & 15);
      ob[nt][ks] = *(const intx4*)(smem + row * 256 + slot * 16);
    }
  }
  if (tid < 64) {
    float s = 0.f;
    #pragma unroll
    for (int j = 0; j < 16; j += 4) {
      float4 a = *(const float4*)(x2p + tid * 16 + j);
      s += a.x + a.y + a.z + a.w;
    }
    x2p[1024 + tid] = s;
  }
  __syncthreads();   // x2 sums visible (last barrier before epilogue)

  float hx2[4];
  #pragma unroll
  for (int nt = 0; nt < 4; ++nt) hx2[nt] = 0.5f * x2p[1024 + nt * 16 + c];

  const intx4 Z4i = {0, 0, 0, 0};
  const floatx4 Z4 = {0.f, 0.f, 0.f, 0.f};
  floatx4 acc2m[2][4], acc2s[2][4];   // 64 regs (AGPR), static indexing only
  #pragma unroll
  for (int a2i = 0; a2i < 2; ++a2i)
    #pragma unroll
    for (int nt = 0; nt < 4; ++nt) {
      acc2m[a2i][nt] = Z4;
      acc2s[a2i][nt] = Z4;
    }

  intx4 a1A[4], a1B[4];
  float4 acA, gcA, acB, gcB;
  u32 pE[4], pc[4];

#define GEMM1T(CF, A1)                                                          \
  { A1[0] = __builtin_amdgcn_mfma_i32_16x16x64_i8(CF[0], ob[0][0], Z4i, 0, 0, 0); \
    A1[1] = __builtin_amdgcn_mfma_i32_16x16x64_i8(CF[0], ob[1][0], Z4i, 0, 0, 0); \
    A1[2] = __builtin_amdgcn_mfma_i32_16x16x64_i8(CF[0], ob[2][0], Z4i, 0, 0, 0); \
    A1[3] = __builtin_amdgcn_mfma_i32_16x16x64_i8(CF[0], ob[3][0], Z4i, 0, 0, 0); \
    _Pragma("unroll")                                                           \
    for (int ks = 1; ks < 4; ++ks) {                                            \
      A1[0] = __builtin_amdgcn_mfma_i32_16x16x64_i8(CF[ks], ob[0][ks], A1[0], 0, 0, 0); \
      A1[1] = __builtin_amdgcn_mfma_i32_16x16x64_i8(CF[ks], ob[1][ks], A1[1], 0, 0, 0); \
      A1[2] = __builtin_amdgcn_mfma_i32_16x16x64_i8(CF[ks], ob[2][ks], A1[2], 0, 0, 0); \
      A1[3] = __builtin_amdgcn_mfma_i32_16x16x64_i8(CF[ks], ob[3][ks], A1[3], 0, 0, 0); \
    } }

#define EXPP(A1, AC, GC, DST)                                                   \
  { _Pragma("unroll")                                                           \
    for (int nt = 0; nt < 4; ++nt) {                                            \
      float t0 = (float)A1[nt][0] - hx2[nt], t1 = (float)A1[nt][1] - hx2[nt];   \
      float t2 = (float)A1[nt][2] - hx2[nt], t3 = (float)A1[nt][3] - hx2[nt];   \
      DST[nt] = pk_fp8(__builtin_amdgcn_exp2f(fmaf(AC.x, t0, GC.x)),            \
                       __builtin_amdgcn_exp2f(fmaf(AC.y, t1, GC.y)),            \
                       __builtin_amdgcn_exp2f(fmaf(AC.z, t2, GC.z)),            \
                       __builtin_amdgcn_exp2f(fmaf(AC.w, t3, GC.w))); } }

#define GEMM2P(ACC, WV4)                                                        \
  { long wA0 = mk64(WV4.x, WV4.y), wA1 = mk64(WV4.z, WV4.w);                    \
    _Pragma("unroll")                                                           \
    for (int nt = 0; nt < 4; ++nt) {                                            \
      long pb = mk64(pE[nt], pc[nt]);                                           \
      ACC[0][nt] = __builtin_amdgcn_mfma_f32_16x16x32_fp8_fp8(wA0, pb, ACC[0][nt], 0, 0, 0); \
      ACC[1][nt] = __builtin_amdgcn_mfma_f32_16x16x32_fp8_fp8(wA1, pb, ACC[1][nt], 0, 0, 0); \
    } }

  // pipeline prologue: tile0 GEMM1 issued, cfU refilled with tile2
  acA = *(const float4*)(a2g + kslc);
  gcA = *(const float4*)(g2n + kslc);
  GEMM1T(cfU, a1A)
  LOADCF(cfU, 2)

  // STEP(m): GEMM1(2m+1) ; exp(2m) ; GEMM1(2m+2) ; exp(2m+1) ; GEMM2(pair m)
#define STEP(m, ACC, DO_U)                                                      \
  {                                                                             \
    const int e = 2 * (m);                                                      \
    uint4 wv4 = *(const uint4*)(wtl + (size_t)(m) * 4096);                      \
    acB = *(const float4*)(a2g + (e + 1) * 64 + kslc);                          \
    gcB = *(const float4*)(g2n + (e + 1) * 64 + kslc);                          \
    GEMM1T(cfV, a1B)                                                            \
    LOADCF(cfV, e + 3)                                                          \
    EXPP(a1A, acA, gcA, pE)                                                     \
    acA = *(const float4*)(a2g + (e + 2) * 64 + kslc);                          \
    gcA = *(const float4*)(g2n + (e + 2) * 64 + kslc);                          \
    GEMM1T(cfU, a1A)                                                            \
    if (DO_U) LOADCF(cfU, e + 4)                                                \
    EXPP(a1B, acB, gcB, pc)                                                     \
    GEMM2P(ACC, wv4)                                                            \
  }

  #pragma unroll
  for (int m = 0; m < 8; ++m) STEP(m, acc2m, 1)
  #pragma unroll
  for (int m = 8; m < 14; ++m) STEP(m, acc2s, 1)
  STEP(14, acc2s, 0)
  // last pair: tiles 30 (in a1A) and 31 (via cfV)
  {
    uint4 wv4 = *(const uint4*)(wtl + (size_t)15 * 4096);
    acB = *(const float4*)(a2g + 31 * 64 + kslc);
    gcB = *(const float4*)(g2n + 31 * 64 + kslc);
    GEMM1T(cfV, a1B)
    EXPP(a1A, acA, gcA, pE)
    EXPP(a1B, acB, gcB, pc)
    GEMM2P(acc2s, wv4)
  }
#undef STEP
#undef GEMM1T
#undef EXPP
#undef GEMM2P
#undef LOADCF

  // ---- epilogue: cross-wave reduction (red aliases obs LDS; K-loop reads no LDS) ----
  // red[wv][b=64][a=68pad]; lane(c,q) reg r holds a = h*32+a2i*16+4q+r, b = nt*16+c
  {
    float* myr = red + wv * 4352;
    #pragma unroll
    for (int a2i = 0; a2i < 2; ++a2i)
      #pragma unroll
      for (int nt = 0; nt < 4; ++nt) {
        *(floatx4*)(myr + (nt * 16 + c) * 68 + a2i * 16 + 4 * q)      = acc2m[a2i][nt];
        *(floatx4*)(myr + (nt * 16 + c) * 68 + 32 + a2i * 16 + 4 * q) = acc2s[a2i][nt];
      }
  }
  __syncthreads();

  #pragma unroll
  for (int i = 0; i < 16; ++i) {
    int idx = tid + 256 * i;        // 0..4095
    int a = idx & 63;
    int b = idx >> 6;
    float v = red[b * 68 + a] + red[4352 + b * 68 + a] +
              red[8704 + b * 68 + a] + red[13056 + b * 68 + a];
    if (a < 32) {
      v += mbias[a];
    } else {
      v += sbias[a - 32];
      v = fminf(fmaxf(v, -20.f), 2.f);
      v = __builtin_amdgcn_exp2f(v * LOG2E);
    }
    out[(size_t)(row0 + b) * 64 + a] = v;
  }
}

extern "C" void kernel_launch(void* const* d_in, const int* in_sizes, int n_in,
                              void* d_out, int out_size, void* d_ws, size_t ws_size,
                              hipStream_t stream) {
  const float* obs = (const float*)d_in[0];
  const float* mC  = (const float*)d_in[1];
  const float* mS  = (const float*)d_in[2];
  const float* mW  = (const float*)d_in[3];
  const float* mB  = (const float*)d_in[4];
  const float* sC  = (const float*)d_in[5];
  const float* sS  = (const float*)d_in[6];
  const float* sW  = (const float*)d_in[7];
  const float* sB  = (const float*)d_in[8];
  float* out = (float*)d_out;

  // workspace: Cb2[2048*256] i8 (512KB) | a2g[2048] f32 | g2n[2048] f32 | wt[64KB]
  u8*    Cb2 = (u8*)d_ws;
  float* a2g = (float*)((char*)d_ws + 2048 * 256);
  float* g2n = a2g + 2048;
  u8*    wt  = (u8*)(g2n + 2048);

  prep<<<528, 256, 0, stream>>>(mC, mS, sC, sS, mW, sW, Cb2, a2g, g2n, wt);
  policy_main<<<512, 256, 0, stream>>>(obs, Cb2, a2g, g2n, wt, mB, sB, out);
}